// Round 2
// baseline (38.583 us; speedup 1.0000x reference)
//
#include <hip/hip_runtime.h>
#include <math.h>

// Volume rendering: R rays, N=192 samples/ray.
// One wavefront (64 lanes) per ray; lane l owns samples {l, l+64, l+128}.
// All global loads hoisted & non-temporal (pure streaming, no reuse).

constexpr int N_SAMP = 192;
constexpr float EPS = 1e-10f;

__global__ __launch_bounds__(256) void render_kernel(
    const float* __restrict__ rgbs,   // (R, N, 3)
    const float* __restrict__ dens,   // (R, N)
    const float* __restrict__ pts,    // (R, N, 3) -- only first 6 floats used
    float* __restrict__ out,          // (R, 3)
    int R)
{
    const int lane = threadIdx.x & 63;
    const int ray  = (blockIdx.x * blockDim.x + threadIdx.x) >> 6;
    if (ray >= R) return;

    const float* __restrict__ d_ray   = dens + (size_t)ray * N_SAMP;
    const float* __restrict__ rgb_ray = rgbs + (size_t)ray * N_SAMP * 3;

    // Issue ALL streaming loads first (12 dwords/lane outstanding).
    float d[3];
#pragma unroll
    for (int j = 0; j < 3; ++j)
        d[j] = __builtin_nontemporal_load(d_ray + j * 64 + lane);

    float r[3][3];
#pragma unroll
    for (int j = 0; j < 3; ++j) {
        const float* __restrict__ p = rgb_ray + (size_t)(j * 64 + lane) * 3;
#pragma unroll
        for (int c = 0; c < 3; ++c)
            r[j][c] = __builtin_nontemporal_load(p + c);
    }

    // delta: scalar step size from ray 0, samples 0 and 1 (uniform address,
    // L2-served broadcast; tiny)
    const float dx = pts[3] - pts[0];
    const float dy = pts[4] - pts[1];
    const float dz = pts[5] - pts[2];
    const float delta = sqrtf(dx * dx + dy * dy + dz * dz);

    // alpha and transmittance factor per owned sample
    float a[3], t[3];
#pragma unroll
    for (int j = 0; j < 3; ++j) {
        const float al = 1.0f - __expf(-d[j] * delta);
        a[j] = al;
        t[j] = 1.0f - al + EPS;
    }

    // exclusive prefix product over sample index (the rolled transmittance),
    // fused with weighted RGB accumulation.
    float sr = 0.0f, sg = 0.0f, sb = 0.0f;
    float carry = 1.0f;  // product of all samples in previous 64-chunks
#pragma unroll
    for (int j = 0; j < 3; ++j) {
        // inclusive product scan of t[j] across 64 lanes
        float incl = t[j];
#pragma unroll
        for (int off = 1; off < 64; off <<= 1) {
            const float up = __shfl_up(incl, off, 64);
            incl *= (lane >= off) ? up : 1.0f;
        }
        // exclusive scan via shift by one lane
        float excl = __shfl_up(incl, 1, 64);
        if (lane == 0) excl = 1.0f;

        const float w = carry * excl * a[j];
        sr += w * r[j][0];
        sg += w * r[j][1];
        sb += w * r[j][2];

        // chunk total product, broadcast from last lane
        carry *= __shfl(incl, 63, 64);
    }

    // wave reduction of the three channel sums
#pragma unroll
    for (int off = 32; off >= 1; off >>= 1) {
        sr += __shfl_down(sr, off, 64);
        sg += __shfl_down(sg, off, 64);
        sb += __shfl_down(sb, off, 64);
    }
    if (lane == 0) {
        float* o = out + (size_t)ray * 3;
        __builtin_nontemporal_store(sr, o + 0);
        __builtin_nontemporal_store(sg, o + 1);
        __builtin_nontemporal_store(sb, o + 2);
    }
}

extern "C" void kernel_launch(void* const* d_in, const int* in_sizes, int n_in,
                              void* d_out, int out_size, void* d_ws, size_t ws_size,
                              hipStream_t stream) {
    const float* rgbs = (const float*)d_in[0];
    const float* dens = (const float*)d_in[1];
    const float* pts  = (const float*)d_in[2];
    float* out = (float*)d_out;

    const int R = in_sizes[1] / N_SAMP;  // densities is (R, N)

    const int waves_per_block = 4;       // 256 threads
    dim3 block(256);
    dim3 grid((R + waves_per_block - 1) / waves_per_block);
    render_kernel<<<grid, block, 0, stream>>>(rgbs, dens, pts, out, R);
}

// Round 3
// 34.247 us; speedup vs baseline: 1.1266x; 1.1266x over previous
//
#include <hip/hip_runtime.h>
#include <math.h>

// Volume rendering: R rays, N=192 samples/ray.
// One wavefront per ray; lane l owns the 3 CONTIGUOUS samples {3l,3l+1,3l+2}.
// -> per-lane contiguous 36B rgb + 12B density reads (wide loads, no gaps),
// -> single 6-step wave-wide product scan (vs 3 chained scans),
// -> weights and rgb colocated in-lane (no redistribution).

constexpr int N_SAMP = 192;  // == 3 * 64
constexpr float EPS = 1e-10f;

__global__ __launch_bounds__(256) void render_kernel(
    const float* __restrict__ rgbs,   // (R, N, 3)
    const float* __restrict__ dens,   // (R, N)
    const float* __restrict__ pts,    // (R, N, 3) -- only first 6 floats used
    float* __restrict__ out,          // (R, 3)
    int R)
{
    const int lane = threadIdx.x & 63;
    const int ray  = (blockIdx.x * blockDim.x + threadIdx.x) >> 6;
    if (ray >= R) return;

    // delta: scalar step size from ray 0, samples 0 and 1 (uniform address)
    const float dx = pts[3] - pts[0];
    const float dy = pts[4] - pts[1];
    const float dz = pts[5] - pts[2];
    const float delta = sqrtf(dx * dx + dy * dy + dz * dz);

    // per-lane contiguous slices
    const float* __restrict__ dp = dens + (size_t)ray * N_SAMP + 3 * lane;
    const float* __restrict__ rp = rgbs + ((size_t)ray * N_SAMP + 3 * lane) * 3;

    float dv[3];
#pragma unroll
    for (int i = 0; i < 3; ++i) dv[i] = dp[i];

    float r[9];
#pragma unroll
    for (int i = 0; i < 9; ++i) r[i] = rp[i];

    // alpha and transmittance factors for the 3 owned samples
    float a[3], t[3];
#pragma unroll
    for (int i = 0; i < 3; ++i) {
        a[i] = 1.0f - __expf(-dv[i] * delta);
        t[i] = 1.0f - a[i] + EPS;
    }

    // wave-wide exclusive product scan over lane-local products
    float incl = t[0] * t[1] * t[2];
#pragma unroll
    for (int off = 1; off < 64; off <<= 1) {
        const float up = __shfl_up(incl, off, 64);
        incl *= (lane >= off) ? up : 1.0f;
    }
    float excl = __shfl_up(incl, 1, 64);   // prod of all samples before 3*lane
    if (lane == 0) excl = 1.0f;

    // in-lane exclusive terms and weights
    const float w0 = excl * a[0];
    const float e1 = excl * t[0];
    const float w1 = e1 * a[1];
    const float w2 = e1 * t[1] * a[2];

    // weighted RGB accumulation, fully in-lane
    float sr = w0 * r[0] + w1 * r[3] + w2 * r[6];
    float sg = w0 * r[1] + w1 * r[4] + w2 * r[7];
    float sb = w0 * r[2] + w1 * r[5] + w2 * r[8];

    // wave reduction of the three channel sums
#pragma unroll
    for (int off = 32; off >= 1; off >>= 1) {
        sr += __shfl_down(sr, off, 64);
        sg += __shfl_down(sg, off, 64);
        sb += __shfl_down(sb, off, 64);
    }
    if (lane == 0) {
        float* o = out + (size_t)ray * 3;
        o[0] = sr;
        o[1] = sg;
        o[2] = sb;
    }
}

extern "C" void kernel_launch(void* const* d_in, const int* in_sizes, int n_in,
                              void* d_out, int out_size, void* d_ws, size_t ws_size,
                              hipStream_t stream) {
    const float* rgbs = (const float*)d_in[0];
    const float* dens = (const float*)d_in[1];
    const float* pts  = (const float*)d_in[2];
    float* out = (float*)d_out;

    const int R = in_sizes[1] / N_SAMP;  // densities is (R, N)

    const int waves_per_block = 4;       // 256 threads
    dim3 block(256);
    dim3 grid((R + waves_per_block - 1) / waves_per_block);
    render_kernel<<<grid, block, 0, stream>>>(rgbs, dens, pts, out, R);
}